// Round 2
// baseline (1702.795 us; speedup 1.0000x reference)
//
#include <hip/hip_runtime.h>
#include <hip/hip_bf16.h>

#define BB 32
#define TT 64
#define NN 512
#define HH 64
#define CC 32

using u16 = unsigned short;
using u32 = unsigned int;

struct alignas(8) US4 { u16 x, y, z, w; };

__device__ __forceinline__ float bf2f(u16 u) {
  union { u32 i; float f; } v; v.i = ((u32)u) << 16; return v.f;
}
__device__ __forceinline__ u16 f2bf(float f) {
  __hip_bfloat16 h = __float2bfloat16(f);
  u16 u; __builtin_memcpy(&u, &h, 2); return u;
}
__device__ __forceinline__ void unpack8f(uint4 q, float* f) {
  f[0] = bf2f(q.x & 0xffff); f[1] = bf2f(q.x >> 16);
  f[2] = bf2f(q.y & 0xffff); f[3] = bf2f(q.y >> 16);
  f[4] = bf2f(q.z & 0xffff); f[5] = bf2f(q.z >> 16);
  f[6] = bf2f(q.w & 0xffff); f[7] = bf2f(q.w >> 16);
}
__device__ __forceinline__ void unpack8u(uint4 q, u16* s) {
  s[0] = q.x & 0xffff; s[1] = q.x >> 16;
  s[2] = q.y & 0xffff; s[3] = q.y >> 16;
  s[4] = q.z & 0xffff; s[5] = q.z >> 16;
  s[6] = q.w & 0xffff; s[7] = q.w >> 16;
}

// ---------------------------------------------------------------------------
// K0: S[bt][u] = sum_v X[bt][v] * adj[u][v]     (S fp32, 2048 x 512)
// grid (32, 8), 256 threads, 64x64 tile, 4x4 microtile. Inputs fp32.
// ---------------------------------------------------------------------------
__global__ __launch_bounds__(256) void k0_s(const float* __restrict__ xg,
                                            const float* __restrict__ adjg,
                                            float* __restrict__ Sg) {
  __shared__ __align__(16) float XsT[64][68];
  __shared__ __align__(16) float AdjT[64][68];
  const int tid = threadIdx.x;
  const int bt0 = blockIdx.x * 64, u0 = blockIdx.y * 64;
  const int ty = tid >> 4, tx = tid & 15;
  const int r = tid >> 2, cb = (tid & 3) << 4;
  float acc[4][4] = {};
  for (int v0 = 0; v0 < NN; v0 += 64) {
    {
      const float4* p = (const float4*)(xg + (((size_t)(bt0 + r)) << 9) + v0 + cb);
#pragma unroll
      for (int q = 0; q < 4; ++q) {
        float4 v = p[q];
        XsT[cb + q * 4 + 0][r] = v.x; XsT[cb + q * 4 + 1][r] = v.y;
        XsT[cb + q * 4 + 2][r] = v.z; XsT[cb + q * 4 + 3][r] = v.w;
      }
      const float4* pa = (const float4*)(adjg + (((size_t)(u0 + r)) << 9) + v0 + cb);
#pragma unroll
      for (int q = 0; q < 4; ++q) {
        float4 v = pa[q];
        AdjT[cb + q * 4 + 0][r] = v.x; AdjT[cb + q * 4 + 1][r] = v.y;
        AdjT[cb + q * 4 + 2][r] = v.z; AdjT[cb + q * 4 + 3][r] = v.w;
      }
    }
    __syncthreads();
#pragma unroll 8
    for (int v = 0; v < 64; ++v) {
      const float4 av = *(const float4*)&XsT[v][ty * 4];
      const float4 bv = *(const float4*)&AdjT[v][tx * 4];
      const float a[4] = {av.x, av.y, av.z, av.w};
      const float b[4] = {bv.x, bv.y, bv.z, bv.w};
#pragma unroll
      for (int i = 0; i < 4; ++i)
#pragma unroll
        for (int j = 0; j < 4; ++j) acc[i][j] += a[i] * b[j];
    }
    __syncthreads();
  }
#pragma unroll
  for (int i = 0; i < 4; ++i) {
    float4 o = {acc[i][0], acc[i][1], acc[i][2], acc[i][3]};
    *(float4*)&Sg[((size_t)(bt0 + ty * 4 + i)) * NN + u0 + tx * 4] = o;
  }
}

// ---------------------------------------------------------------------------
// K1: G[s][h] = sum_c relu(w1[c]*S[s] + b1[c]) * w2[c][h]   (G bf16, chunk)
// grid (CB*T*N/64), 256 threads. Weights fp32.
// ---------------------------------------------------------------------------
__global__ __launch_bounds__(256) void k1_g(const float* __restrict__ Sg,
                                            const float* __restrict__ w1g,
                                            const float* __restrict__ b1g,
                                            const float* __restrict__ w2g,
                                            u16* __restrict__ Gg, int sBase) {
  __shared__ __align__(16) float RsT[32][68];
  __shared__ __align__(16) float w2s[32][64];
  const int tid = threadIdx.x;
  const int s0 = blockIdx.x * 64;
  {
    const int c = tid >> 3, hb = (tid & 7) << 3;
    const float4* p = (const float4*)(w2g + c * 64 + hb);
    float4 v0 = p[0], v1 = p[1];
    w2s[c][hb + 0] = v0.x; w2s[c][hb + 1] = v0.y;
    w2s[c][hb + 2] = v0.z; w2s[c][hb + 3] = v0.w;
    w2s[c][hb + 4] = v1.x; w2s[c][hb + 5] = v1.y;
    w2s[c][hb + 6] = v1.z; w2s[c][hb + 7] = v1.w;
  }
  {
    const int sL = tid & 63, cb0 = (tid >> 6) << 3;
    const float sv = Sg[(size_t)sBase + s0 + sL];
#pragma unroll
    for (int q = 0; q < 8; ++q) {
      const int c = cb0 + q;
      RsT[c][sL] = fmaxf(fmaf(w1g[c], sv, b1g[c]), 0.f);
    }
  }
  __syncthreads();
  const int ty = tid >> 4, tx = tid & 15;
  float acc[4][4] = {};
#pragma unroll 8
  for (int c = 0; c < 32; ++c) {
    const float4 av = *(const float4*)&RsT[c][ty * 4];
    const float4 bv = *(const float4*)&w2s[c][tx * 4];
    const float a[4] = {av.x, av.y, av.z, av.w};
    const float b[4] = {bv.x, bv.y, bv.z, bv.w};
#pragma unroll
    for (int i = 0; i < 4; ++i)
#pragma unroll
      for (int j = 0; j < 4; ++j) acc[i][j] += a[i] * b[j];
  }
#pragma unroll
  for (int i = 0; i < 4; ++i) {
    US4 o = {f2bf(acc[i][0]), f2bf(acc[i][1]), f2bf(acc[i][2]), f2bf(acc[i][3])};
    *(US4*)&Gg[((size_t)(s0 + ty * 4 + i)) * HH + tx * 4] = o;
  }
}

// ---------------------------------------------------------------------------
// K2: h2[b'][u][t][h] = relu(sum_v adj[u][v] * G[b'][t][v][h] + b2[h])
// grid (8, 64, CB), 256 threads. adj/b2 fp32, G bf16 in ws.
// Output layout [b'][u][t][h] (bf16) so K3 reads contiguously.
// ---------------------------------------------------------------------------
__global__ __launch_bounds__(256) void k2_h2(const float* __restrict__ adjg,
                                             const u16* __restrict__ Gg,
                                             const float* __restrict__ b2g,
                                             u16* __restrict__ H2g) {
  __shared__ __align__(16) float AdjT[64][68];
  __shared__ __align__(16) float Gs[64][64];
  const int tid = threadIdx.x;
  const int u0 = blockIdx.x * 64;
  const int t = blockIdx.y;
  const int bp = blockIdx.z;
  const size_t gBase = (((size_t)bp * TT + t) * NN) * HH;
  const int ty = tid >> 4, tx = tid & 15;
  const int r = tid >> 2, cb = (tid & 3) << 4;
  float acc[4][4] = {};
  for (int v0 = 0; v0 < NN; v0 += 64) {
    {
      const float4* pa = (const float4*)(adjg + (((size_t)(u0 + r)) << 9) + v0 + cb);
#pragma unroll
      for (int q = 0; q < 4; ++q) {
        float4 v = pa[q];
        AdjT[cb + q * 4 + 0][r] = v.x; AdjT[cb + q * 4 + 1][r] = v.y;
        AdjT[cb + q * 4 + 2][r] = v.z; AdjT[cb + q * 4 + 3][r] = v.w;
      }
      const u16* p = Gg + gBase + (((size_t)(v0 + r)) << 6) + cb;
      uint4 q0 = *(const uint4*)p, q1 = *(const uint4*)(p + 8);
      float f[16]; unpack8f(q0, f); unpack8f(q1, f + 8);
#pragma unroll
      for (int j = 0; j < 16; ++j) Gs[r][cb + j] = f[j];
    }
    __syncthreads();
#pragma unroll 8
    for (int v = 0; v < 64; ++v) {
      const float4 av = *(const float4*)&AdjT[v][ty * 4];
      const float4 bv = *(const float4*)&Gs[v][tx * 4];
      const float a[4] = {av.x, av.y, av.z, av.w};
      const float b[4] = {bv.x, bv.y, bv.z, bv.w};
#pragma unroll
      for (int i = 0; i < 4; ++i)
#pragma unroll
        for (int j = 0; j < 4; ++j) acc[i][j] += a[i] * b[j];
    }
    __syncthreads();
  }
  float b2v[4];
#pragma unroll
  for (int j = 0; j < 4; ++j) b2v[j] = b2g[tx * 4 + j];
#pragma unroll
  for (int i = 0; i < 4; ++i) {
    const int u = u0 + ty * 4 + i;
    US4 o = {f2bf(fmaxf(acc[i][0] + b2v[0], 0.f)),
             f2bf(fmaxf(acc[i][1] + b2v[1], 0.f)),
             f2bf(fmaxf(acc[i][2] + b2v[2], 0.f)),
             f2bf(fmaxf(acc[i][3] + b2v[3], 0.f))};
    *(US4*)&H2g[(((size_t)bp * NN + u) * TT + t) * HH + tx * 4] = o;
  }
}

// ---------------------------------------------------------------------------
// K3: per (b', n): conv[ho][t] = sum_{hi,k} W[n,ho,hi,k]*Hin[hi][t+k-1]
//     pred[b][n] = sum_{ho,t} relu(conv + tcn_b) * fc_w[ho*T+t] + fc_b
// grid (512, CB), 256 threads. Weights fp32, Hin bf16, out fp32.
// ---------------------------------------------------------------------------
__global__ __launch_bounds__(256) void k3_tcn(const u16* __restrict__ H2g,
                                              const float* __restrict__ twg,
                                              const float* __restrict__ tbg,
                                              const float* __restrict__ fwg,
                                              const float* __restrict__ fbg,
                                              float* __restrict__ outg, int b0) {
  __shared__ u16 HinS[64][68];                    // [h][t+1], zero-padded borders
  __shared__ __align__(16) float WsT[3][64][68];  // [k][hi][ho]
  __shared__ float red[4];
  const int tid = threadIdx.x;
  const int n = blockIdx.x, bp = blockIdx.y;
  // stage Hin (transpose [t][h] -> [h][t+1])
  {
    const int t = tid >> 2, hb = (tid & 3) << 4;
    const u16* p = H2g + (((size_t)bp * NN + n) * TT + t) * HH + hb;
    uint4 q0 = *(const uint4*)p, q1 = *(const uint4*)(p + 8);
    u16 us[16]; unpack8u(q0, us); unpack8u(q1, us + 8);
#pragma unroll
    for (int j = 0; j < 16; ++j) HinS[hb + j][t + 1] = us[j];
    if (tid < 64) { HinS[tid][0] = 0; HinS[tid][65] = 0; }
  }
  // stage W: tcn_w[(n*64+ho)*192 + hi*3 + k] -> WsT[k][hi][ho]   (fp32)
  {
    const float4* p = (const float4*)(twg + (size_t)n * (HH * HH * 3) + tid * 48);
#pragma unroll
    for (int q = 0; q < 12; ++q) {
      float4 v = p[q];
      const float f[4] = {v.x, v.y, v.z, v.w};
#pragma unroll
      for (int j = 0; j < 4; ++j) {
        const int e = tid * 48 + q * 4 + j;
        const int ho = e / 192;
        const int rem = e - ho * 192;
        const int hi = rem / 3;
        const int k = rem - hi * 3;
        WsT[k][hi][ho] = f[j];
      }
    }
  }
  __syncthreads();
  const int ty = tid >> 4, tx = tid & 15;
  float acc[4][4] = {};
#pragma unroll 2
  for (int hi = 0; hi < 64; ++hi) {
    const float4 a0v = *(const float4*)&WsT[0][hi][ty * 4];
    const float4 a1v = *(const float4*)&WsT[1][hi][ty * 4];
    const float4 a2v = *(const float4*)&WsT[2][hi][ty * 4];
    const float a0[4] = {a0v.x, a0v.y, a0v.z, a0v.w};
    const float a1[4] = {a1v.x, a1v.y, a1v.z, a1v.w};
    const float a2[4] = {a2v.x, a2v.y, a2v.z, a2v.w};
    float hw[6];
#pragma unroll
    for (int m = 0; m < 6; ++m) hw[m] = bf2f(HinS[hi][tx * 4 + m]);
#pragma unroll
    for (int i = 0; i < 4; ++i)
#pragma unroll
      for (int j = 0; j < 4; ++j)
        acc[i][j] += a0[i] * hw[j] + a1[i] * hw[j + 1] + a2[i] * hw[j + 2];
  }
  // epilogue: bias + relu + FC dot
  float part = 0.f;
  float tb[4];
#pragma unroll
  for (int i = 0; i < 4; ++i) tb[i] = tbg[n * HH + ty * 4 + i];
#pragma unroll
  for (int i = 0; i < 4; ++i)
#pragma unroll
    for (int j = 0; j < 4; ++j) {
      const float cv = fmaxf(acc[i][j] + tb[i], 0.f);
      part += cv * fwg[(ty * 4 + i) * TT + tx * 4 + j];
    }
#pragma unroll
  for (int off = 32; off > 0; off >>= 1) part += __shfl_xor(part, off, 64);
  const int wid = tid >> 6, lane = tid & 63;
  if (lane == 0) red[wid] = part;
  __syncthreads();
  if (tid == 0) {
    const float tot = red[0] + red[1] + red[2] + red[3] + fbg[0];
    outg[(size_t)(b0 + bp) * NN + n] = tot;
  }
}

// ---------------------------------------------------------------------------
extern "C" void kernel_launch(void* const* d_in, const int* in_sizes, int n_in,
                              void* d_out, int out_size, void* d_ws, size_t ws_size,
                              hipStream_t stream) {
  const float* xg   = (const float*)d_in[0];
  const float* adjg = (const float*)d_in[1];
  const float* w1g  = (const float*)d_in[2];
  const float* b1g  = (const float*)d_in[3];
  const float* w2g  = (const float*)d_in[4];
  const float* b2g  = (const float*)d_in[5];
  const float* twg  = (const float*)d_in[6];
  const float* tbg  = (const float*)d_in[7];
  const float* fwg  = (const float*)d_in[8];
  const float* fbg  = (const float*)d_in[9];
  float* outg = (float*)d_out;

  // workspace: S (fp32, all batches) | G (bf16, CB batches) | H2T (bf16, CB batches)
  const size_t sBytes = (size_t)BB * TT * NN * sizeof(float);  // 4 MiB
  const size_t perB   = (size_t)TT * NN * HH * sizeof(u16);    // 4 MiB each
  int CB = 32;
  while (CB > 1 && sBytes + (size_t)CB * 2 * perB > ws_size) CB >>= 1;

  float* Sg = (float*)d_ws;
  u16* Gg  = (u16*)((char*)d_ws + sBytes);
  u16* H2g = Gg + (size_t)CB * TT * NN * HH;

  k0_s<<<dim3(BB * TT / 64, NN / 64), 256, 0, stream>>>(xg, adjg, Sg);
  for (int b0 = 0; b0 < BB; b0 += CB) {
    k1_g<<<dim3(CB * TT * NN / 64), 256, 0, stream>>>(Sg, w1g, b1g, w2g, Gg, b0 * TT * NN);
    k2_h2<<<dim3(NN / 64, TT, CB), 256, 0, stream>>>(adjg, Gg, b2g, H2g);
    k3_tcn<<<dim3(NN, CB), 256, 0, stream>>>(H2g, twg, tbg, fwg, fbg, outg, b0);
  }
}

// Round 3
// 485.485 us; speedup vs baseline: 3.5074x; 3.5074x over previous
//
#include <hip/hip_runtime.h>
#include <hip/hip_bf16.h>

#define BB 32
#define TT 64
#define NN 512
#define HH 64

using u16 = unsigned short;
using u32 = unsigned int;
typedef __attribute__((ext_vector_type(8))) short bf16x8;
typedef __attribute__((ext_vector_type(4))) float f32x4;

__device__ __forceinline__ float bf2f(u16 u) {
  union { u32 i; float f; } v; v.i = ((u32)u) << 16; return v.f;
}
__device__ __forceinline__ u16 f2bf(float f) {
  __hip_bfloat16 h = __float2bfloat16(f);
  u16 u; __builtin_memcpy(&u, &h, 2); return u;
}

// async global->LDS, 16B per lane; lds base must be wave-uniform,
// lane i lands at ldsbase + i*16 (no per-lane scatter).
__device__ __forceinline__ void gld_lds16(const void* g, void* l) {
  __builtin_amdgcn_global_load_lds(
      (const __attribute__((address_space(1))) u32*)g,
      (__attribute__((address_space(3))) u32*)l, 16, 0, 0);
}

// ---------------------------------------------------------------------------
// conversion kernels (run once per call)
// ---------------------------------------------------------------------------
__global__ __launch_bounds__(256) void kcvt_adj(const float* __restrict__ a,
                                                u16* __restrict__ o) {
  const int i = blockIdx.x * 256 + threadIdx.x;  // 262144 total
  o[i] = f2bf(a[i]);
}
__global__ __launch_bounds__(256) void kcvt_w2t(const float* __restrict__ w2,
                                                u16* __restrict__ o) {
  const int i = blockIdx.x * 256 + threadIdx.x;  // 2048 total, o[h*32+c]
  const int h = i >> 5, c = i & 31;
  o[i] = f2bf(w2[c * 64 + h]);
}
// tcn_w [n][ho][hi][kk] (fp32) -> Wb [n][kk][ho][hi] (bf16)
__global__ __launch_bounds__(256) void kcvt_w(const float* __restrict__ tw,
                                              u16* __restrict__ o) {
  const int i = blockIdx.x * 256 + threadIdx.x;  // 6291456 total
  const int hi = i & 63;
  const int ho = (i >> 6) & 63;
  const int r = i >> 12;  // n*3 + kk
  const int n = r / 3, kk = r - n * 3;
  o[i] = f2bf(tw[(n * 64 + ho) * 192 + hi * 3 + kk]);
}

// ---------------------------------------------------------------------------
// K0: S[bt][u] = sum_v X[bt][v] * adj[u][v]   (fp32 VALU, 1.07 GF — cheap)
// ---------------------------------------------------------------------------
__global__ __launch_bounds__(256) void k0_s(const float* __restrict__ xg,
                                            const float* __restrict__ adjg,
                                            float* __restrict__ Sg) {
  __shared__ __align__(16) float XsT[64][68];
  __shared__ __align__(16) float AdjT[64][68];
  const int tid = threadIdx.x;
  const int bt0 = blockIdx.x * 64, u0 = blockIdx.y * 64;
  const int ty = tid >> 4, tx = tid & 15;
  const int r = tid >> 2, cb = (tid & 3) << 4;
  float acc[4][4] = {};
  for (int v0 = 0; v0 < NN; v0 += 64) {
    {
      const float4* p = (const float4*)(xg + (((size_t)(bt0 + r)) << 9) + v0 + cb);
#pragma unroll
      for (int q = 0; q < 4; ++q) {
        float4 v = p[q];
        XsT[cb + q * 4 + 0][r] = v.x; XsT[cb + q * 4 + 1][r] = v.y;
        XsT[cb + q * 4 + 2][r] = v.z; XsT[cb + q * 4 + 3][r] = v.w;
      }
      const float4* pa = (const float4*)(adjg + (((size_t)(u0 + r)) << 9) + v0 + cb);
#pragma unroll
      for (int q = 0; q < 4; ++q) {
        float4 v = pa[q];
        AdjT[cb + q * 4 + 0][r] = v.x; AdjT[cb + q * 4 + 1][r] = v.y;
        AdjT[cb + q * 4 + 2][r] = v.z; AdjT[cb + q * 4 + 3][r] = v.w;
      }
    }
    __syncthreads();
#pragma unroll 8
    for (int v = 0; v < 64; ++v) {
      const float4 av = *(const float4*)&XsT[v][ty * 4];
      const float4 bv = *(const float4*)&AdjT[v][tx * 4];
      const float a[4] = {av.x, av.y, av.z, av.w};
      const float b[4] = {bv.x, bv.y, bv.z, bv.w};
#pragma unroll
      for (int i = 0; i < 4; ++i)
#pragma unroll
        for (int j = 0; j < 4; ++j) acc[i][j] += a[i] * b[j];
    }
    __syncthreads();
  }
#pragma unroll
  for (int i = 0; i < 4; ++i) {
    float4 o = {acc[i][0], acc[i][1], acc[i][2], acc[i][3]};
    *(float4*)&Sg[((size_t)(bt0 + ty * 4 + i)) * NN + u0 + tx * 4] = o;
  }
}

// ---------------------------------------------------------------------------
// K1 (MFMA): G[(bp,t,h)][v] = sum_c relu(w1[c]*S[bt,v]+b1[c]) * w2[c][h]
// grid (T, CB); per wave: 64h x 128v, K=32 in one MFMA step, B built in-reg.
// ---------------------------------------------------------------------------
__global__ __launch_bounds__(256) void k1_g(const float* __restrict__ Sg,
                                            const float* __restrict__ w1g,
                                            const float* __restrict__ b1g,
                                            const u16* __restrict__ w2t,
                                            u16* __restrict__ Gg, int b0) {
  const int tid = threadIdx.x;
  const int t = blockIdx.x, bp = blockIdx.y;
  const int w = tid >> 6, l = tid & 63;
  const int quad = l >> 4, lr = l & 15;
  const size_t sRow = ((size_t)((b0 + bp) * TT + t)) * NN;
  const size_t gBase = ((size_t)(bp * TT + t)) * HH * NN;
  float w1v[8], b1v[8];
#pragma unroll
  for (int j = 0; j < 8; ++j) { w1v[j] = w1g[quad * 8 + j]; b1v[j] = b1g[quad * 8 + j]; }
  bf16x8 af[4];
#pragma unroll
  for (int i = 0; i < 4; ++i)
    af[i] = *(const bf16x8*)(w2t + (i * 16 + lr) * 32 + quad * 8);
  const f32x4 zz = {0.f, 0.f, 0.f, 0.f};
  for (int vp = 0; vp < 2; ++vp) {
    const int v0 = w * 128 + vp * 64;
    f32x4 acc[4][4];
#pragma unroll
    for (int i = 0; i < 4; ++i)
#pragma unroll
      for (int j = 0; j < 4; ++j) acc[i][j] = zz;
    bf16x8 bfr[4];
#pragma unroll
    for (int j = 0; j < 4; ++j) {
      const int v = v0 + j * 16 + lr;
      const float sv = Sg[sRow + v];
      bf16x8 x;
#pragma unroll
      for (int jj = 0; jj < 8; ++jj)
        x[jj] = (short)f2bf(fmaxf(fmaf(w1v[jj], sv, b1v[jj]), 0.f));
      bfr[j] = x;
    }
#pragma unroll
    for (int i = 0; i < 4; ++i)
#pragma unroll
      for (int j = 0; j < 4; ++j)
        acc[i][j] = __builtin_amdgcn_mfma_f32_16x16x32_bf16(af[i], bfr[j], acc[i][j], 0, 0, 0);
#pragma unroll
    for (int i = 0; i < 4; ++i)
#pragma unroll
      for (int j = 0; j < 4; ++j) {
        const int v = v0 + j * 16 + lr;
#pragma unroll
        for (int r = 0; r < 4; ++r) {
          const int h = i * 16 + quad * 4 + r;
          Gg[gBase + (size_t)h * NN + v] = f2bf(acc[i][j][r]);
        }
      }
  }
}

// ---------------------------------------------------------------------------
// K2 (MFMA GEMM, m97-style): C[u][n] = relu(sum_v A[u][v]*B[n][v] + b2[n&63])
// A = adj bf16 [512][512], B = G [Nc][512], C = H2 bf16 [512][Nc].
// 128x128 tile, BK=64, global_load_lds w16, XOR-swizzled LDS, 2x2 waves.
// ---------------------------------------------------------------------------
__global__ __launch_bounds__(256) void k2_gemm(const u16* __restrict__ A,
                                               const u16* __restrict__ Bm,
                                               const float* __restrict__ b2g,
                                               u16* __restrict__ C, int Nc) {
  __shared__ __align__(16) char smem[32768];  // As 16KB | Bs 16KB
  const int tid = threadIdx.x;
  const int w = tid >> 6, l = tid & 63;
  const int quad = l >> 4, lr = l & 15;
  const int tn = blockIdx.x, tm = blockIdx.y;
  const int m0 = tm * 128, n0 = tn * 128;
  const int wm = w >> 1, wn = w & 1;
  // staging: inst (w,c) covers rows c*32+w*8 .. +8, lane i -> (row base+i>>3, unit i&7)
  const int rB = w * 8 + (l >> 3);
  const int uu = l & 7;
  const u16* agp[4]; const u16* bgp[4];
#pragma unroll
  for (int c = 0; c < 4; ++c) {
    const int r = rB + c * 32;
    agp[c] = A + (size_t)(m0 + r) * 512 + ((uu ^ (r & 7)) * 8);
    bgp[c] = Bm + (size_t)(n0 + r) * 512 + ((uu ^ (r & 7)) * 8);
  }
  char* As = smem;
  char* Bs = smem + 16384;
  int arow[4], brow[4];
#pragma unroll
  for (int i = 0; i < 4; ++i) {
    arow[i] = (wm * 64 + i * 16 + lr) * 128;
    brow[i] = (wn * 64 + i * 16 + lr) * 128;
  }
  const f32x4 zz = {0.f, 0.f, 0.f, 0.f};
  f32x4 acc[4][4];
#pragma unroll
  for (int i = 0; i < 4; ++i)
#pragma unroll
    for (int j = 0; j < 4; ++j) acc[i][j] = zz;
  const int lx7 = lr & 7;
  for (int kt = 0; kt < 8; ++kt) {
#pragma unroll
    for (int c = 0; c < 4; ++c) {
      gld_lds16(agp[c] + kt * 64, As + (c * 32 + w * 8) * 128);
      gld_lds16(bgp[c] + kt * 64, Bs + (c * 32 + w * 8) * 128);
    }
    __syncthreads();
#pragma unroll
    for (int ks = 0; ks < 2; ++ks) {
      const int coff = (((ks * 4 + quad) ^ lx7)) * 16;
      bf16x8 afr[4], bfr[4];
#pragma unroll
      for (int i = 0; i < 4; ++i) afr[i] = *(const bf16x8*)(As + arow[i] + coff);
#pragma unroll
      for (int j = 0; j < 4; ++j) bfr[j] = *(const bf16x8*)(Bs + brow[j] + coff);
#pragma unroll
      for (int i = 0; i < 4; ++i)
#pragma unroll
        for (int j = 0; j < 4; ++j)
          acc[i][j] = __builtin_amdgcn_mfma_f32_16x16x32_bf16(afr[i], bfr[j], acc[i][j], 0, 0, 0);
    }
    __syncthreads();
  }
  float bias[4];
#pragma unroll
  for (int j = 0; j < 4; ++j) bias[j] = b2g[j * 16 + lr];  // h = j*16+lr
#pragma unroll
  for (int i = 0; i < 4; ++i) {
    const int u0r = m0 + wm * 64 + i * 16 + quad * 4;
#pragma unroll
    for (int j = 0; j < 4; ++j) {
      const int n = n0 + wn * 64 + j * 16 + lr;
#pragma unroll
      for (int r = 0; r < 4; ++r) {
        const float vv = fmaxf(acc[i][j][r] + bias[j], 0.f);
        C[(size_t)(u0r + r) * Nc + n] = f2bf(vv);
      }
    }
  }
}

// ---------------------------------------------------------------------------
// K3 (MFMA): per (n, bp): out = sum over conv(k=3) with W[n][kk][ho][hi],
// B = H2 slab [t][h] (already K-contiguous), 3 shifted K=64 GEMMs, fused FC.
// ---------------------------------------------------------------------------
__global__ __launch_bounds__(256) void k3_tcn(const u16* __restrict__ H2,
                                              const u16* __restrict__ Wb,
                                              const float* __restrict__ tbg,
                                              const float* __restrict__ fwg,
                                              const float* __restrict__ fbg,
                                              float* __restrict__ outg,
                                              int b0, int Nc) {
  __shared__ float red[4];
  const int tid = threadIdx.x;
  const int n = blockIdx.x, bp = blockIdx.y;
  const int w = tid >> 6, l = tid & 63;
  const int quad = l >> 4, lr = l & 15;
  const u16* Wp = Wb + (size_t)n * 12288;
  const u16* Hs = H2 + (size_t)n * Nc + bp * 4096;
  const f32x4 zz = {0.f, 0.f, 0.f, 0.f};
  f32x4 acc[4];
#pragma unroll
  for (int tnn = 0; tnn < 4; ++tnn) acc[tnn] = zz;
  bf16x8 bz;
#pragma unroll
  for (int jj = 0; jj < 8; ++jj) bz[jj] = 0;
#pragma unroll
  for (int kk = 0; kk < 3; ++kk)
#pragma unroll
    for (int ks = 0; ks < 2; ++ks) {
      const int hi = ks * 32 + quad * 8;
      const bf16x8 af = *(const bf16x8*)(Wp + kk * 4096 + (w * 16 + lr) * 64 + hi);
#pragma unroll
      for (int tnn = 0; tnn < 4; ++tnn) {
        const int tau = tnn * 16 + lr + kk - 1;
        bf16x8 bfr = bz;
        if (tau >= 0 && tau < 64) bfr = *(const bf16x8*)(Hs + tau * 64 + hi);
        acc[tnn] = __builtin_amdgcn_mfma_f32_16x16x32_bf16(af, bfr, acc[tnn], 0, 0, 0);
      }
    }
  float tb[4];
#pragma unroll
  for (int r = 0; r < 4; ++r) tb[r] = tbg[n * 64 + w * 16 + quad * 4 + r];
  float part = 0.f;
#pragma unroll
  for (int tnn = 0; tnn < 4; ++tnn)
#pragma unroll
    for (int r = 0; r < 4; ++r) {
      const int ho = w * 16 + quad * 4 + r;
      const int t = tnn * 16 + lr;
      part += fmaxf(acc[tnn][r] + tb[r], 0.f) * fwg[ho * 64 + t];
    }
#pragma unroll
  for (int off = 32; off > 0; off >>= 1) part += __shfl_xor(part, off, 64);
  if (l == 0) red[w] = part;
  __syncthreads();
  if (tid == 0)
    outg[(size_t)(b0 + bp) * NN + n] = red[0] + red[1] + red[2] + red[3] + fbg[0];
}

// ---------------------------------------------------------------------------
extern "C" void kernel_launch(void* const* d_in, const int* in_sizes, int n_in,
                              void* d_out, int out_size, void* d_ws, size_t ws_size,
                              hipStream_t stream) {
  const float* xg   = (const float*)d_in[0];
  const float* adjg = (const float*)d_in[1];
  const float* w1g  = (const float*)d_in[2];
  const float* b1g  = (const float*)d_in[3];
  const float* w2g  = (const float*)d_in[4];
  const float* b2g  = (const float*)d_in[5];
  const float* twg  = (const float*)d_in[6];
  const float* tbg  = (const float*)d_in[7];
  const float* fwg  = (const float*)d_in[8];
  const float* fbg  = (const float*)d_in[9];
  float* outg = (float*)d_out;

  char* ws = (char*)d_ws;
  float* Sg = (float*)ws;                      // 4,194,304 B
  u16* adjb = (u16*)(ws + 4194304);            //   524,288 B
  u16* w2t  = (u16*)(ws + 4718592);            //     8,192 B (4KB used)
  u16* Wb   = (u16*)(ws + 4726784);            // 12,582,912 B
  const size_t fixedB = 17309696;
  int CB = 32;
  while (CB > 1 && fixedB + (size_t)CB * 8388608ull > ws_size) CB >>= 1;
  u16* Gg  = (u16*)(ws + fixedB);
  u16* H2g = Gg + (size_t)CB * 2097152;  // CB*4096 rows x 512
  const int Nc = CB * 4096;

  kcvt_adj<<<1024, 256, 0, stream>>>(adjg, adjb);
  kcvt_w2t<<<8, 256, 0, stream>>>(w2g, w2t);
  kcvt_w<<<24576, 256, 0, stream>>>(twg, Wb);
  k0_s<<<dim3(BB * TT / 64, NN / 64), 256, 0, stream>>>(xg, adjg, Sg);
  for (int b0 = 0; b0 < BB; b0 += CB) {
    k1_g<<<dim3(TT, CB), 256, 0, stream>>>(Sg, w1g, b1g, w2t, Gg, b0);
    k2_gemm<<<dim3(Nc / 128, 4), 256, 0, stream>>>(adjb, Gg, b2g, H2g, Nc);
    k3_tcn<<<dim3(NN, CB), 256, 0, stream>>>(H2g, Wb, tbg, fwg, fbg, outg, b0, Nc);
  }
}

// Round 4
// 405.606 us; speedup vs baseline: 4.1981x; 1.1969x over previous
//
#include <hip/hip_runtime.h>
#include <hip/hip_bf16.h>

#define BB 32
#define TT 64
#define NN 512
#define HH 64

using u16 = unsigned short;
using u32 = unsigned int;
typedef __attribute__((ext_vector_type(8))) short bf16x8;
typedef __attribute__((ext_vector_type(4))) float f32x4;

__device__ __forceinline__ float bf2f(u16 u) {
  union { u32 i; float f; } v; v.i = ((u32)u) << 16; return v.f;
}
__device__ __forceinline__ u16 f2bf(float f) {
  __hip_bfloat16 h = __float2bfloat16(f);
  u16 u; __builtin_memcpy(&u, &h, 2); return u;
}

// async global->LDS, 16B per lane; lds base must be wave-uniform,
// lane i lands at ldsbase + i*16 (no per-lane scatter).
__device__ __forceinline__ void gld_lds16(const void* g, void* l) {
  __builtin_amdgcn_global_load_lds(
      (const __attribute__((address_space(1))) u32*)g,
      (__attribute__((address_space(3))) u32*)l, 16, 0, 0);
}

// ---------------------------------------------------------------------------
// conversion kernels (run once per call)
// ---------------------------------------------------------------------------
__global__ __launch_bounds__(256) void kcvt_adj(const float* __restrict__ a,
                                                u16* __restrict__ o) {
  const int i = blockIdx.x * 256 + threadIdx.x;  // 262144 total
  o[i] = f2bf(a[i]);
}
__global__ __launch_bounds__(256) void kcvt_w2t(const float* __restrict__ w2,
                                                u16* __restrict__ o) {
  const int i = blockIdx.x * 256 + threadIdx.x;  // 2048 total, o[h*32+c]
  const int h = i >> 5, c = i & 31;
  o[i] = f2bf(w2[c * 64 + h]);
}
// tcn_w [n][ho][hi][kk] (fp32) -> Wb [n][kk][ho][hi] (bf16)
__global__ __launch_bounds__(256) void kcvt_w(const float* __restrict__ tw,
                                              u16* __restrict__ o) {
  const int i = blockIdx.x * 256 + threadIdx.x;  // 6291456 total
  const int hi = i & 63;
  const int ho = (i >> 6) & 63;
  const int r = i >> 12;  // n*3 + kk
  const int n = r / 3, kk = r - n * 3;
  o[i] = f2bf(tw[(n * 64 + ho) * 192 + hi * 3 + kk]);
}

// ---------------------------------------------------------------------------
// K0: S[bt][u] = sum_v X[bt][v] * adj[u][v]   (fp32 VALU, 1.07 GF — cheap)
// ---------------------------------------------------------------------------
__global__ __launch_bounds__(256) void k0_s(const float* __restrict__ xg,
                                            const float* __restrict__ adjg,
                                            float* __restrict__ Sg) {
  __shared__ __align__(16) float XsT[64][68];
  __shared__ __align__(16) float AdjT[64][68];
  const int tid = threadIdx.x;
  const int bt0 = blockIdx.x * 64, u0 = blockIdx.y * 64;
  const int ty = tid >> 4, tx = tid & 15;
  const int r = tid >> 2, cb = (tid & 3) << 4;
  float acc[4][4] = {};
  for (int v0 = 0; v0 < NN; v0 += 64) {
    {
      const float4* p = (const float4*)(xg + (((size_t)(bt0 + r)) << 9) + v0 + cb);
#pragma unroll
      for (int q = 0; q < 4; ++q) {
        float4 v = p[q];
        XsT[cb + q * 4 + 0][r] = v.x; XsT[cb + q * 4 + 1][r] = v.y;
        XsT[cb + q * 4 + 2][r] = v.z; XsT[cb + q * 4 + 3][r] = v.w;
      }
      const float4* pa = (const float4*)(adjg + (((size_t)(u0 + r)) << 9) + v0 + cb);
#pragma unroll
      for (int q = 0; q < 4; ++q) {
        float4 v = pa[q];
        AdjT[cb + q * 4 + 0][r] = v.x; AdjT[cb + q * 4 + 1][r] = v.y;
        AdjT[cb + q * 4 + 2][r] = v.z; AdjT[cb + q * 4 + 3][r] = v.w;
      }
    }
    __syncthreads();
#pragma unroll 8
    for (int v = 0; v < 64; ++v) {
      const float4 av = *(const float4*)&XsT[v][ty * 4];
      const float4 bv = *(const float4*)&AdjT[v][tx * 4];
      const float a[4] = {av.x, av.y, av.z, av.w};
      const float b[4] = {bv.x, bv.y, bv.z, bv.w};
#pragma unroll
      for (int i = 0; i < 4; ++i)
#pragma unroll
        for (int j = 0; j < 4; ++j) acc[i][j] += a[i] * b[j];
    }
    __syncthreads();
  }
#pragma unroll
  for (int i = 0; i < 4; ++i) {
    float4 o = {acc[i][0], acc[i][1], acc[i][2], acc[i][3]};
    *(float4*)&Sg[((size_t)(bt0 + ty * 4 + i)) * NN + u0 + tx * 4] = o;
  }
}

// ---------------------------------------------------------------------------
// K1 (MFMA): G[(bp,t,h)][v] = sum_c relu(w1[c]*S[bt,v]+b1[c]) * w2[c][h]
// grid (T, CB); per wave: 64h x 128v, K=32 in one MFMA step, B built in-reg.
// ---------------------------------------------------------------------------
__global__ __launch_bounds__(256) void k1_g(const float* __restrict__ Sg,
                                            const float* __restrict__ w1g,
                                            const float* __restrict__ b1g,
                                            const u16* __restrict__ w2t,
                                            u16* __restrict__ Gg, int b0) {
  const int tid = threadIdx.x;
  const int t = blockIdx.x, bp = blockIdx.y;
  const int w = tid >> 6, l = tid & 63;
  const int quad = l >> 4, lr = l & 15;
  const size_t sRow = ((size_t)((b0 + bp) * TT + t)) * NN;
  const size_t gBase = ((size_t)(bp * TT + t)) * HH * NN;
  float w1v[8], b1v[8];
#pragma unroll
  for (int j = 0; j < 8; ++j) { w1v[j] = w1g[quad * 8 + j]; b1v[j] = b1g[quad * 8 + j]; }
  bf16x8 af[4];
#pragma unroll
  for (int i = 0; i < 4; ++i)
    af[i] = *(const bf16x8*)(w2t + (i * 16 + lr) * 32 + quad * 8);
  const f32x4 zz = {0.f, 0.f, 0.f, 0.f};
  for (int vp = 0; vp < 2; ++vp) {
    const int v0 = w * 128 + vp * 64;
    f32x4 acc[4][4];
#pragma unroll
    for (int i = 0; i < 4; ++i)
#pragma unroll
      for (int j = 0; j < 4; ++j) acc[i][j] = zz;
    bf16x8 bfr[4];
#pragma unroll
    for (int j = 0; j < 4; ++j) {
      const int v = v0 + j * 16 + lr;
      const float sv = Sg[sRow + v];
      bf16x8 x;
#pragma unroll
      for (int jj = 0; jj < 8; ++jj)
        x[jj] = (short)f2bf(fmaxf(fmaf(w1v[jj], sv, b1v[jj]), 0.f));
      bfr[j] = x;
    }
#pragma unroll
    for (int i = 0; i < 4; ++i)
#pragma unroll
      for (int j = 0; j < 4; ++j)
        acc[i][j] = __builtin_amdgcn_mfma_f32_16x16x32_bf16(af[i], bfr[j], acc[i][j], 0, 0, 0);
#pragma unroll
    for (int i = 0; i < 4; ++i)
#pragma unroll
      for (int j = 0; j < 4; ++j) {
        const int v = v0 + j * 16 + lr;
#pragma unroll
        for (int r = 0; r < 4; ++r) {
          const int h = i * 16 + quad * 4 + r;
          Gg[gBase + (size_t)h * NN + v] = f2bf(acc[i][j][r]);
        }
      }
  }
}

// ---------------------------------------------------------------------------
// K2 (MFMA GEMM, m97-style): C[u][n] = relu(sum_v A[u][v]*B[n][v] + b2[n&63])
// A = adj bf16 [512][512], B = G [Nc][512], C = H2 bf16 [512][Nc].
// 128x128 tile, BK=64, global_load_lds w16, XOR-swizzled LDS, 2x2 waves.
// ---------------------------------------------------------------------------
__global__ __launch_bounds__(256) void k2_gemm(const u16* __restrict__ A,
                                               const u16* __restrict__ Bm,
                                               const float* __restrict__ b2g,
                                               u16* __restrict__ C, int Nc) {
  __shared__ __align__(16) char smem[32768];  // As 16KB | Bs 16KB
  const int tid = threadIdx.x;
  const int w = tid >> 6, l = tid & 63;
  const int quad = l >> 4, lr = l & 15;
  const int tn = blockIdx.x, tm = blockIdx.y;
  const int m0 = tm * 128, n0 = tn * 128;
  const int wm = w >> 1, wn = w & 1;
  // staging: inst (w,c) covers rows c*32+w*8 .. +8, lane i -> (row base+i>>3, unit i&7)
  const int rB = w * 8 + (l >> 3);
  const int uu = l & 7;
  const u16* agp[4]; const u16* bgp[4];
#pragma unroll
  for (int c = 0; c < 4; ++c) {
    const int r = rB + c * 32;
    agp[c] = A + (size_t)(m0 + r) * 512 + ((uu ^ (r & 7)) * 8);
    bgp[c] = Bm + (size_t)(n0 + r) * 512 + ((uu ^ (r & 7)) * 8);
  }
  char* As = smem;
  char* Bs = smem + 16384;
  int arow[4], brow[4];
#pragma unroll
  for (int i = 0; i < 4; ++i) {
    arow[i] = (wm * 64 + i * 16 + lr) * 128;
    brow[i] = (wn * 64 + i * 16 + lr) * 128;
  }
  const f32x4 zz = {0.f, 0.f, 0.f, 0.f};
  f32x4 acc[4][4];
#pragma unroll
  for (int i = 0; i < 4; ++i)
#pragma unroll
    for (int j = 0; j < 4; ++j) acc[i][j] = zz;
  const int lx7 = lr & 7;
  for (int kt = 0; kt < 8; ++kt) {
#pragma unroll
    for (int c = 0; c < 4; ++c) {
      gld_lds16(agp[c] + kt * 64, As + (c * 32 + w * 8) * 128);
      gld_lds16(bgp[c] + kt * 64, Bs + (c * 32 + w * 8) * 128);
    }
    __syncthreads();
#pragma unroll
    for (int ks = 0; ks < 2; ++ks) {
      const int coff = (((ks * 4 + quad) ^ lx7)) * 16;
      bf16x8 afr[4], bfr[4];
#pragma unroll
      for (int i = 0; i < 4; ++i) afr[i] = *(const bf16x8*)(As + arow[i] + coff);
#pragma unroll
      for (int j = 0; j < 4; ++j) bfr[j] = *(const bf16x8*)(Bs + brow[j] + coff);
#pragma unroll
      for (int i = 0; i < 4; ++i)
#pragma unroll
        for (int j = 0; j < 4; ++j)
          acc[i][j] = __builtin_amdgcn_mfma_f32_16x16x32_bf16(afr[i], bfr[j], acc[i][j], 0, 0, 0);
    }
    __syncthreads();
  }
  float bias[4];
#pragma unroll
  for (int j = 0; j < 4; ++j) bias[j] = b2g[j * 16 + lr];  // h = j*16+lr
#pragma unroll
  for (int i = 0; i < 4; ++i) {
    const int u0r = m0 + wm * 64 + i * 16 + quad * 4;
#pragma unroll
    for (int j = 0; j < 4; ++j) {
      const int n = n0 + wn * 64 + j * 16 + lr;
#pragma unroll
      for (int r = 0; r < 4; ++r) {
        const float vv = fmaxf(acc[i][j][r] + bias[j], 0.f);
        C[(size_t)(u0r + r) * Nc + n] = f2bf(vv);
      }
    }
  }
}

// ---------------------------------------------------------------------------
// K3 (MFMA, wave-per-(n,bp)): conv as 3 shifted K=64 GEMMs, M=64 ho, N=64 t,
// W frags register-resident, B frags reused 4x across ho-tiles, fused FC.
// grid (NN, ceil(CB/4)), 4 waves/block = 4 bp. No LDS, no barrier.
// ---------------------------------------------------------------------------
__global__ __launch_bounds__(256) void k3_tcn(const u16* __restrict__ H2,
                                              const u16* __restrict__ Wb,
                                              const float* __restrict__ tbg,
                                              const float* __restrict__ fwg,
                                              const float* __restrict__ fbg,
                                              float* __restrict__ outg,
                                              int b0, int Nc, int CBcur) {
  const int tid = threadIdx.x;
  const int n = blockIdx.x;
  const int w = tid >> 6, l = tid & 63;
  const int bp = blockIdx.y * 4 + w;
  if (bp >= CBcur) return;
  const int quad = l >> 4, lr = l & 15;
  const u16* Wp = Wb + (size_t)n * 12288;
  const u16* Hs = H2 + (size_t)n * Nc + bp * 4096;
  const f32x4 zz = {0.f, 0.f, 0.f, 0.f};
  f32x4 acc[4][4];
#pragma unroll
  for (int i = 0; i < 4; ++i)
#pragma unroll
    for (int j = 0; j < 4; ++j) acc[i][j] = zz;
  bf16x8 bz;
#pragma unroll
  for (int jj = 0; jj < 8; ++jj) bz[jj] = 0;
#pragma unroll
  for (int kk = 0; kk < 3; ++kk)
#pragma unroll
    for (int ks = 0; ks < 2; ++ks) {
      const int hi = ks * 32 + quad * 8;
      bf16x8 af[4], bfr[4];
#pragma unroll
      for (int i = 0; i < 4; ++i)
        af[i] = *(const bf16x8*)(Wp + kk * 4096 + (i * 16 + lr) * 64 + hi);
#pragma unroll
      for (int j = 0; j < 4; ++j) {
        const int tau = j * 16 + lr + kk - 1;
        const int tc = min(max(tau, 0), 63);
        const bf16x8 v = *(const bf16x8*)(Hs + tc * 64 + hi);
        bfr[j] = (tau == tc) ? v : bz;
      }
#pragma unroll
      for (int i = 0; i < 4; ++i)
#pragma unroll
        for (int j = 0; j < 4; ++j)
          acc[i][j] = __builtin_amdgcn_mfma_f32_16x16x32_bf16(af[i], bfr[j], acc[i][j], 0, 0, 0);
    }
  // epilogue: bias + relu + FC dot, all in-wave
  float part = 0.f;
#pragma unroll
  for (int i = 0; i < 4; ++i) {
    const float4 tb = *(const float4*)(tbg + n * 64 + i * 16 + quad * 4);
    const float tbv[4] = {tb.x, tb.y, tb.z, tb.w};
#pragma unroll
    for (int r = 0; r < 4; ++r) {
      const int ho = i * 16 + quad * 4 + r;
#pragma unroll
      for (int j = 0; j < 4; ++j) {
        const int t = j * 16 + lr;
        part += fmaxf(acc[i][j][r] + tbv[r], 0.f) * fwg[ho * 64 + t];
      }
    }
  }
#pragma unroll
  for (int off = 32; off > 0; off >>= 1) part += __shfl_xor(part, off, 64);
  if (l == 0) outg[(size_t)(b0 + bp) * NN + n] = part + fbg[0];
}

// ---------------------------------------------------------------------------
extern "C" void kernel_launch(void* const* d_in, const int* in_sizes, int n_in,
                              void* d_out, int out_size, void* d_ws, size_t ws_size,
                              hipStream_t stream) {
  const float* xg   = (const float*)d_in[0];
  const float* adjg = (const float*)d_in[1];
  const float* w1g  = (const float*)d_in[2];
  const float* b1g  = (const float*)d_in[3];
  const float* w2g  = (const float*)d_in[4];
  const float* b2g  = (const float*)d_in[5];
  const float* twg  = (const float*)d_in[6];
  const float* tbg  = (const float*)d_in[7];
  const float* fwg  = (const float*)d_in[8];
  const float* fbg  = (const float*)d_in[9];
  float* outg = (float*)d_out;

  char* ws = (char*)d_ws;
  float* Sg = (float*)ws;                      // 4,194,304 B
  u16* adjb = (u16*)(ws + 4194304);            //   524,288 B
  u16* w2t  = (u16*)(ws + 4718592);            //     8,192 B (4KB used)
  u16* Wb   = (u16*)(ws + 4726784);            // 12,582,912 B
  const size_t fixedB = 17309696;
  int CB = 32;
  while (CB > 1 && fixedB + (size_t)CB * 8388608ull > ws_size) CB >>= 1;
  u16* Gg  = (u16*)(ws + fixedB);
  u16* H2g = Gg + (size_t)CB * 2097152;  // CB*4096 rows x 512
  const int Nc = CB * 4096;

  kcvt_adj<<<1024, 256, 0, stream>>>(adjg, adjb);
  kcvt_w2t<<<8, 256, 0, stream>>>(w2g, w2t);
  kcvt_w<<<24576, 256, 0, stream>>>(twg, Wb);
  k0_s<<<dim3(BB * TT / 64, NN / 64), 256, 0, stream>>>(xg, adjg, Sg);
  for (int b0 = 0; b0 < BB; b0 += CB) {
    k1_g<<<dim3(TT, CB), 256, 0, stream>>>(Sg, w1g, b1g, w2t, Gg, b0);
    k2_gemm<<<dim3(Nc / 128, 4), 256, 0, stream>>>(adjb, Gg, b2g, H2g, Nc);
    k3_tcn<<<dim3(NN, (CB + 3) / 4), 256, 0, stream>>>(H2g, Wb, tbg, fwg, fbg, outg, b0, Nc, CB);
  }
}